// Round 1
// baseline (15856.989 us; speedup 1.0000x reference)
//
#include <hip/hip_runtime.h>
#include <math.h>

#define B_TOT 256
#define L_SEQ 256
#define DM 256
#define DI 512
#define DS 16
#define NL 6
#define MLPH 128
#define ED 64

__device__ __forceinline__ float f_sigmoid(float x){ return 1.f/(1.f+__expf(-x)); }
__device__ __forceinline__ float f_silu(float x){ return x/(1.f+__expf(-x)); }
__device__ __forceinline__ float f_softplus(float x){ return x>20.f ? x : log1pf(__expf(x)); }

// ---------- embedding + conv(k=3, pad 1/1) + affine + relu ----------
__global__ __launch_bounds__(256) void k_embed_conv(
    const int* __restrict__ tok, const float* __restrict__ emb,
    const float* __restrict__ cw, const float* __restrict__ gamma,
    const float* __restrict__ beta, float* __restrict__ out)
{
  const int b  = blockIdx.y;
  const int lt = blockIdx.x;          // tile of 16 positions
  const int tid = threadIdx.x;        // output channel o (0..255)
  __shared__ float xs[18][ED];
  for (int idx = tid; idx < 18*ED; idx += 256){
    int t = idx / ED, i = idx - t*ED;
    int l = lt*16 + t - 1;
    float v = 0.f;
    if (l >= 0 && l < L_SEQ) v = emb[tok[b*L_SEQ + l]*ED + i];
    xs[t][i] = v;
  }
  __syncthreads();
  const float g  = gamma[tid] * rsqrtf(1.001f);
  const float bt = beta[tid];
  const float* w = cw + (size_t)tid*(ED*3);
  float acc[16];
  #pragma unroll
  for (int t=0;t<16;t++) acc[t]=0.f;
  for (int i=0;i<ED;i++){
    float w0 = w[i*3+0], w1 = w[i*3+1], w2 = w[i*3+2];
    #pragma unroll
    for (int t=0;t<16;t++)
      acc[t] += xs[t][i]*w0 + xs[t+1][i]*w1 + xs[t+2][i]*w2;
  }
  #pragma unroll
  for (int t=0;t<16;t++){
    float v = acc[t]*g + bt;
    out[((size_t)(b*L_SEQ + lt*16 + t))*DM + tid] = fmaxf(v, 0.f);
  }
}

// ---------- fused residual-add + rmsnorm (wave per row, 4 rows/block) ----------
template<bool FIRST>
__global__ __launch_bounds__(256) void k_add_rmsnorm(
    const float* __restrict__ x, float* __restrict__ residual,
    const float* __restrict__ w, float* out)
{
  const int row  = blockIdx.x*4 + (threadIdx.x >> 6);
  const int lane = threadIdx.x & 63;
  const size_t base = (size_t)row*DM;
  float4 v = ((const float4*)(x + base))[lane];
  if (!FIRST){
    float4 r = ((const float4*)(residual + base))[lane];
    v.x += r.x; v.y += r.y; v.z += r.z; v.w += r.w;
  }
  ((float4*)(residual + base))[lane] = v;
  float ss = v.x*v.x + v.y*v.y + v.z*v.z + v.w*v.w;
  #pragma unroll
  for (int m=1; m<64; m<<=1) ss += __shfl_xor(ss, m);
  const float sc = rsqrtf(ss*(1.f/DM) + 1e-4f);
  float4 wv = ((const float4*)w)[lane];
  float4 o;
  o.x = v.x*sc*wv.x; o.y = v.y*sc*wv.y; o.z = v.z*sc*wv.z; o.w = v.w*sc*wv.w;
  ((float4*)(out + base))[lane] = o;
}

// ---------- final layernorm(hidden+residual) ----------
__global__ __launch_bounds__(256) void k_final_ln(
    const float* __restrict__ x, const float* __restrict__ residual,
    const float* __restrict__ w, const float* __restrict__ bb, float* __restrict__ out)
{
  const int row  = blockIdx.x*4 + (threadIdx.x >> 6);
  const int lane = threadIdx.x & 63;
  const size_t base = (size_t)row*DM;
  float4 v = ((const float4*)(x + base))[lane];
  float4 r = ((const float4*)(residual + base))[lane];
  v.x += r.x; v.y += r.y; v.z += r.z; v.w += r.w;
  float s = v.x + v.y + v.z + v.w;
  #pragma unroll
  for (int m=1; m<64; m<<=1) s += __shfl_xor(s, m);
  const float mu = s*(1.f/DM);
  float4 c; c.x=v.x-mu; c.y=v.y-mu; c.z=v.z-mu; c.w=v.w-mu;
  float ss = c.x*c.x + c.y*c.y + c.z*c.z + c.w*c.w;
  #pragma unroll
  for (int m=1; m<64; m<<=1) ss += __shfl_xor(ss, m);
  const float sc = rsqrtf(ss*(1.f/DM) + 1e-4f);
  float4 wv = ((const float4*)w)[lane];
  float4 bv = ((const float4*)bb)[lane];
  float4 o;
  o.x = c.x*sc*wv.x + bv.x; o.y = c.y*sc*wv.y + bv.y;
  o.z = c.z*sc*wv.z + bv.z; o.w = c.w*sc*wv.w + bv.w;
  ((float4*)(out + base))[lane] = o;
}

// ---------- generic f32 GEMM: C[M,N] = A[M,K] @ W[N,K]^T ----------
// grid: (N/64 (ceil), M/64); 256 threads; 4x4 micro-tile per thread
__global__ __launch_bounds__(256) void k_gemm(
    const float* __restrict__ A, const float* __restrict__ W,
    float* __restrict__ C, int N, int K)
{
  const int n0 = blockIdx.x * 64;
  const int m0 = blockIdx.y * 64;
  const int tid = threadIdx.x;
  const int tm = tid >> 4, tn = tid & 15;
  __shared__ float As[16][68];
  __shared__ float Ws[16][68];
  float acc[4][4];
  #pragma unroll
  for (int i=0;i<4;i++)
    #pragma unroll
    for (int j=0;j<4;j++) acc[i][j]=0.f;
  const int ldy = tid >> 2, ldx = tid & 3;
  for (int k0 = 0; k0 < K; k0 += 16){
    __syncthreads();
    {
      float4 av = *(const float4*)(A + (size_t)(m0+ldy)*K + k0 + ldx*4);
      As[ldx*4+0][ldy]=av.x; As[ldx*4+1][ldy]=av.y;
      As[ldx*4+2][ldy]=av.z; As[ldx*4+3][ldy]=av.w;
      float4 wv = make_float4(0.f,0.f,0.f,0.f);
      if (n0 + ldy < N) wv = *(const float4*)(W + (size_t)(n0+ldy)*K + k0 + ldx*4);
      Ws[ldx*4+0][ldy]=wv.x; Ws[ldx*4+1][ldy]=wv.y;
      Ws[ldx*4+2][ldy]=wv.z; Ws[ldx*4+3][ldy]=wv.w;
    }
    __syncthreads();
    #pragma unroll
    for (int kk=0;kk<16;kk++){
      float4 a = *(const float4*)&As[kk][tm*4];
      float4 w = *(const float4*)&Ws[kk][tn*4];
      float av_[4]={a.x,a.y,a.z,a.w}, wv_[4]={w.x,w.y,w.z,w.w};
      #pragma unroll
      for (int i=0;i<4;i++)
        #pragma unroll
        for (int j=0;j<4;j++)
          acc[i][j] = fmaf(av_[i], wv_[j], acc[i][j]);
    }
  }
  const int nc = n0 + tn*4;
  if (nc < N){
    #pragma unroll
    for (int i=0;i<4;i++){
      float4 o = make_float4(acc[i][0],acc[i][1],acc[i][2],acc[i][3]);
      *(float4*)(C + (size_t)(m0 + tm*4 + i)*N + nc) = o;
    }
  }
}

// ---------- causal depthwise conv1d (k=4, pad 3 left) + silu ----------
// xi lives in xz rows of stride 2*DI (cols 0..DI-1)
__global__ __launch_bounds__(256) void k_conv1d_silu(
    const float* __restrict__ xz, const float* __restrict__ cw,
    const float* __restrict__ cb, float* __restrict__ xc)
{
  const int idx = blockIdx.x*256 + threadIdx.x;   // over Mc*DI
  const int d = idx & (DI-1);
  const int m = idx >> 9;
  const int l = m & (L_SEQ-1);
  const float w0=cw[d*4+0], w1=cw[d*4+1], w2=cw[d*4+2], w3=cw[d*4+3];
  float acc = cb[d];
  const size_t rs = 2*DI;
  if (l >= 3) acc += w0 * xz[(size_t)(m-3)*rs + d];
  if (l >= 2) acc += w1 * xz[(size_t)(m-2)*rs + d];
  if (l >= 1) acc += w2 * xz[(size_t)(m-1)*rs + d];
  acc += w3 * xz[(size_t)m*rs + d];
  xc[(size_t)m*DI + d] = f_silu(acc);
}

// ---------- dt = softplus(dt_raw @ dtw^T + dtb), K=16 ----------
__global__ __launch_bounds__(256) void k_dtproj(
    const float* __restrict__ xdbl, const float* __restrict__ dtw,
    const float* __restrict__ dtb, float* __restrict__ dt)
{
  const int idx = blockIdx.x*256 + threadIdx.x;   // over Mc*DI
  const int d = idx & (DI-1);
  const size_t m = (size_t)(idx >> 9);
  const float* xr = xdbl + m*48;
  const float* wr = dtw + (size_t)d*16;
  float acc = dtb[d];
  #pragma unroll
  for (int k=0;k<16;k++) acc += xr[k]*wr[k];
  dt[(size_t)idx] = f_softplus(acc);
}

// ---------- selective scan, fused with y=(ys+u*D)*silu(z); writes y over dt ----------
__global__ __launch_bounds__(256) void k_scan(
    const float* __restrict__ xdbl, const float* __restrict__ xc,
    const float* __restrict__ xz, float* __restrict__ dty,
    const float* __restrict__ A_log, const float* __restrict__ Dp)
{
  const int b = blockIdx.x;
  const int d = blockIdx.y*256 + threadIdx.x;
  __shared__ float BC[2][32];
  float Areg[DS];
  bool structured = true;
  #pragma unroll
  for (int n=0;n<DS;n++){
    Areg[n] = -__expf(A_log[(size_t)d*DS + n]);
    structured = structured && (fabsf(Areg[n] + (float)(n+1)) < 1e-4f*(float)(n+1));
  }
  const float Dv = Dp[d];
  float h[DS];
  #pragma unroll
  for (int n=0;n<DS;n++) h[n]=0.f;
  const size_t rowbase = (size_t)b*L_SEQ;
  if (threadIdx.x < 32) BC[0][threadIdx.x] = xdbl[rowbase*48 + 16 + threadIdx.x];
  float dt_n = dty[rowbase*DI + d];
  float u_n  = xc [rowbase*DI + d];
  float z_n  = xz [rowbase*(2*DI) + DI + d];
  __syncthreads();
  for (int l=0;l<L_SEQ;l++){
    const int cur = l & 1;
    const float dt_v = dt_n, u_v = u_n, z_v = z_n;
    if (l+1 < L_SEQ){
      if (threadIdx.x < 32) BC[cur^1][threadIdx.x] = xdbl[(rowbase+l+1)*48 + 16 + threadIdx.x];
      dt_n = dty[(rowbase+l+1)*DI + d];
      u_n  = xc [(rowbase+l+1)*DI + d];
      z_n  = xz [(rowbase+l+1)*(2*DI) + DI + d];
    }
    const float dtu = dt_v * u_v;
    float y = 0.f;
    if (structured){
      const float p = __expf(-dt_v);
      float pk = 1.f;
      #pragma unroll
      for (int n=0;n<DS;n++){
        pk *= p;
        h[n] = pk*h[n] + dtu*BC[cur][n];
        y += h[n]*BC[cur][16+n];
      }
    } else {
      #pragma unroll
      for (int n=0;n<DS;n++){
        float dA = __expf(dt_v*Areg[n]);
        h[n] = dA*h[n] + dtu*BC[cur][n];
        y += h[n]*BC[cur][16+n];
      }
    }
    dty[(rowbase+l)*DI + d] = (y + u_v*Dv) * f_silu(z_v);
    __syncthreads();
  }
}

// ---------- GLU: out = yg[:, :128] * silu(yg[:, 128:]) ----------
__global__ __launch_bounds__(256) void k_glu(
    const float* __restrict__ yg, float* __restrict__ out)
{
  const int idx = blockIdx.x*256 + threadIdx.x;   // over Mc*MLPH
  const int j = idx & (MLPH-1);
  const size_t m = (size_t)(idx >> 7);
  float a = yg[m*(2*MLPH) + j];
  float g = yg[m*(2*MLPH) + MLPH + j];
  out[(size_t)idx] = a * f_silu(g);
}

// ---------- masked mean pool over L ----------
__global__ __launch_bounds__(256) void k_pool(
    const float* __restrict__ zf, const int* __restrict__ mask,
    float* __restrict__ pool, int b0)
{
  const int b = blockIdx.x;           // chunk-local
  const int d = threadIdx.x;
  __shared__ float mrow[L_SEQ];
  for (int l = d; l < L_SEQ; l += 256) mrow[l] = (float)mask[(size_t)(b0+b)*L_SEQ + l];
  __syncthreads();
  float s = 0.f, ms = 0.f;
  for (int l=0;l<L_SEQ;l++){
    float mv = mrow[l];
    s  += mv * zf[((size_t)b*L_SEQ + l)*DM + d];
    ms += mv;
  }
  pool[(size_t)(b0+b)*DM + d] = s/ms;
}

// ---------- bind head: sigmoid(pool @ bw^T + bb) ----------
__global__ __launch_bounds__(64) void k_bind(
    const float* __restrict__ pool, const float* __restrict__ bw,
    const float* __restrict__ bb, float* __restrict__ out)
{
  const int b = blockIdx.x;
  const int lane = threadIdx.x;
  float4 p = ((const float4*)(pool + (size_t)b*DM))[lane];
  #pragma unroll
  for (int j=0;j<3;j++){
    float4 w = ((const float4*)(bw + (size_t)j*DM))[lane];
    float s = p.x*w.x + p.y*w.y + p.z*w.z + p.w*w.w;
    #pragma unroll
    for (int m=1;m<64;m<<=1) s += __shfl_xor(s, m);
    if (lane==0) out[b*3 + j] = f_sigmoid(s + bb[j]);
  }
}

extern "C" void kernel_launch(void* const* d_in, const int* in_sizes, int n_in,
                              void* d_out, int out_size, void* d_ws, size_t ws_size,
                              hipStream_t stream)
{
  const int*   tok       = (const int*)  d_in[0];
  const int*   mask      = (const int*)  d_in[1];
  const float* emb       = (const float*)d_in[2];
  const float* conv_w    = (const float*)d_in[3];
  const float* bn_gamma  = (const float*)d_in[4];
  const float* bn_beta   = (const float*)d_in[5];
  const float* in_proj_w = (const float*)d_in[6];
  const float* conv1d_w  = (const float*)d_in[7];
  const float* conv1d_b  = (const float*)d_in[8];
  const float* x_proj_w  = (const float*)d_in[9];
  const float* dt_proj_w = (const float*)d_in[10];
  const float* dt_proj_b = (const float*)d_in[11];
  const float* A_log     = (const float*)d_in[12];
  const float* Dp        = (const float*)d_in[13];
  const float* out_proj_w= (const float*)d_in[14];
  const float* norm1_w   = (const float*)d_in[15];
  const float* norm2_w   = (const float*)d_in[16];
  const float* fc1_w     = (const float*)d_in[17];
  const float* fc2_w     = (const float*)d_in[18];
  const float* normf_w   = (const float*)d_in[19];
  const float* normf_b   = (const float*)d_in[20];
  const float* bind_w    = (const float*)d_in[21];
  const float* bind_b    = (const float*)d_in[22];
  float* outp = (float*)d_out;

  // per-batch-row float count: residual,hs,hidden (DM each) + xz(2DI) + xc,dt (DI) + xdbl(48)
  const size_t perB = (size_t)L_SEQ * (3*DM + 2*DI + 2*DI + 48);
  int Bc = B_TOT;
  while (Bc > 1 && ((size_t)Bc*perB + (size_t)B_TOT*DM)*4 > ws_size) Bc >>= 1;
  const int Mc = Bc * L_SEQ;

  float* ws       = (float*)d_ws;
  float* residual = ws;
  float* hs       = residual + (size_t)Mc*DM;
  float* xz       = hs       + (size_t)Mc*DM;
  float* xc       = xz       + (size_t)Mc*(2*DI);
  float* dty      = xc       + (size_t)Mc*DI;
  float* xdbl     = dty      + (size_t)Mc*DI;
  float* hidden   = xdbl     + (size_t)Mc*48;
  float* pool     = hidden   + (size_t)Mc*DM;
  // reuse of xz region after scan consumes it:
  float* mamba_out = xz;                    // Mc*DM
  float* yg        = xz + (size_t)Mc*DM;    // Mc*2*MLPH = Mc*DM
  float* glu       = xz + (size_t)2*Mc*DM;  // Mc*MLPH

  const int nchunks = B_TOT / Bc;
  for (int c = 0; c < nchunks; ++c){
    const int b0 = c * Bc;
    k_embed_conv<<<dim3(L_SEQ/16, Bc), 256, 0, stream>>>(
        tok + (size_t)b0*L_SEQ, emb, conv_w, bn_gamma, bn_beta, hidden);

    for (int i = 0; i < NL; ++i){
      const float* inw  = in_proj_w + (size_t)i*(2*DI)*DM;
      const float* cw   = conv1d_w  + (size_t)i*DI*4;
      const float* cb   = conv1d_b  + (size_t)i*DI;
      const float* xpw  = x_proj_w  + (size_t)i*48*DI;
      const float* dtw  = dt_proj_w + (size_t)i*DI*16;
      const float* dtb  = dt_proj_b + (size_t)i*DI;
      const float* Alg  = A_log     + (size_t)i*DI*DS;
      const float* Dpt  = Dp        + (size_t)i*DI;
      const float* outw = out_proj_w+ (size_t)i*DM*DI;
      const float* n1w  = norm1_w   + (size_t)i*DM;
      const float* n2w  = norm2_w   + (size_t)i*DM;
      const float* f1w  = fc1_w     + (size_t)i*(2*MLPH)*DM;
      const float* f2w  = fc2_w     + (size_t)i*DM*MLPH;

      if (i == 0)
        k_add_rmsnorm<true ><<<Mc/4, 256, 0, stream>>>(hidden, residual, n1w, hs);
      else
        k_add_rmsnorm<false><<<Mc/4, 256, 0, stream>>>(hidden, residual, n1w, hs);

      k_gemm<<<dim3((2*DI)/64, Mc/64), 256, 0, stream>>>(hs, inw, xz, 2*DI, DM);
      k_conv1d_silu<<<(Mc*DI)/256, 256, 0, stream>>>(xz, cw, cb, xc);
      k_gemm<<<dim3(1, Mc/64), 256, 0, stream>>>(xc, xpw, xdbl, 48, DI);
      k_dtproj<<<(Mc*DI)/256, 256, 0, stream>>>(xdbl, dtw, dtb, dty);
      k_scan<<<dim3(Bc, DI/256), 256, 0, stream>>>(xdbl, xc, xz, dty, Alg, Dpt);
      k_gemm<<<dim3(DM/64, Mc/64), 256, 0, stream>>>(dty, outw, mamba_out, DM, DI);
      k_add_rmsnorm<false><<<Mc/4, 256, 0, stream>>>(mamba_out, residual, n2w, hs);
      k_gemm<<<dim3((2*MLPH)/64, Mc/64), 256, 0, stream>>>(hs, f1w, yg, 2*MLPH, DM);
      k_glu<<<(Mc*MLPH)/256, 256, 0, stream>>>(yg, glu);
      k_gemm<<<dim3(DM/64, Mc/64), 256, 0, stream>>>(glu, f2w, hidden, DM, MLPH);
    }

    k_final_ln<<<Mc/4, 256, 0, stream>>>(hidden, residual, normf_w, normf_b, hs);
    k_pool<<<Bc, 256, 0, stream>>>(hs, mask, pool, b0);
  }
  k_bind<<<B_TOT, 64, 0, stream>>>(pool, bind_w, bind_b, outp);
}

// Round 2
// 7107.510 us; speedup vs baseline: 2.2310x; 2.2310x over previous
//
#include <hip/hip_runtime.h>
#include <math.h>

#define B_TOT 256
#define L_SEQ 256
#define DM 256
#define DI 512
#define DS 16
#define NL 6
#define MLPH 128
#define ED 64

typedef unsigned short u16;
typedef unsigned int   u32;
using bf16x8 = __attribute__((ext_vector_type(8))) short;
using f32x4  = __attribute__((ext_vector_type(4))) float;

__device__ __forceinline__ float f_sigmoid(float x){ return 1.f/(1.f+__expf(-x)); }
__device__ __forceinline__ float f_silu(float x){ return x/(1.f+__expf(-x)); }
__device__ __forceinline__ float f_softplus(float x){ return x>20.f ? x : log1pf(__expf(x)); }
__device__ __forceinline__ u16 f2bf(float x){
  union { float f; u32 u; } v; v.f = x;
  u32 r = v.u + 0x7fffu + ((v.u >> 16) & 1u);
  return (u16)(r >> 16);
}
__device__ __forceinline__ float bf2f(u16 h){
  union { u32 u; float f; } v; v.u = ((u32)h) << 16; return v.f;
}

// ---------- weight conversion ----------
__global__ __launch_bounds__(256) void k_cvt(const float* __restrict__ s, u16* __restrict__ d, int n){
  int i = blockIdx.x*256 + threadIdx.x;
  if (i < n) d[i] = f2bf(s[i]);
}
// x_proj: (NL,48,512) -> padded (NL,64,512) bf16, rows 48..63 zero
__global__ __launch_bounds__(256) void k_cvt_xproj(const float* __restrict__ s, u16* __restrict__ d){
  int i = blockIdx.x*256 + threadIdx.x;      // over NL*64*512
  int k = i & 511; int n = (i>>9) & 63; int l = i >> 15;
  d[i] = (n < 48) ? f2bf(s[((size_t)l*48 + n)*512 + k]) : (u16)0;
}

// ---------- embedding + conv(k=3) + affine + relu ----------
__global__ __launch_bounds__(256) void k_embed_conv(
    const int* __restrict__ tok, const float* __restrict__ emb,
    const float* __restrict__ cw, const float* __restrict__ gamma,
    const float* __restrict__ beta, float* __restrict__ out)
{
  const int b  = blockIdx.y;
  const int lt = blockIdx.x;
  const int tid = threadIdx.x;
  __shared__ float xs[18][ED];
  for (int idx = tid; idx < 18*ED; idx += 256){
    int t = idx / ED, i = idx - t*ED;
    int l = lt*16 + t - 1;
    float v = 0.f;
    if (l >= 0 && l < L_SEQ) v = emb[tok[b*L_SEQ + l]*ED + i];
    xs[t][i] = v;
  }
  __syncthreads();
  const float g  = gamma[tid] * rsqrtf(1.001f);
  const float bt = beta[tid];
  const float* w = cw + (size_t)tid*(ED*3);
  float acc[16];
  #pragma unroll
  for (int t=0;t<16;t++) acc[t]=0.f;
  for (int i=0;i<ED;i++){
    float w0 = w[i*3+0], w1 = w[i*3+1], w2 = w[i*3+2];
    #pragma unroll
    for (int t=0;t<16;t++)
      acc[t] += xs[t][i]*w0 + xs[t+1][i]*w1 + xs[t+2][i]*w2;
  }
  #pragma unroll
  for (int t=0;t<16;t++){
    float v = acc[t]*g + bt;
    out[((size_t)(b*L_SEQ + lt*16 + t))*DM + tid] = fmaxf(v, 0.f);
  }
}

// ---------- residual add + rmsnorm -> bf16 out ----------
template<bool FIRST>
__global__ __launch_bounds__(256) void k_add_rmsnorm(
    const float* __restrict__ x, float* __restrict__ residual,
    const float* __restrict__ w, u16* __restrict__ out)
{
  const int row  = blockIdx.x*4 + (threadIdx.x >> 6);
  const int lane = threadIdx.x & 63;
  const size_t base = (size_t)row*DM;
  float4 v = ((const float4*)(x + base))[lane];
  if (!FIRST){
    float4 r = ((const float4*)(residual + base))[lane];
    v.x += r.x; v.y += r.y; v.z += r.z; v.w += r.w;
  }
  ((float4*)(residual + base))[lane] = v;
  float ss = v.x*v.x + v.y*v.y + v.z*v.z + v.w*v.w;
  #pragma unroll
  for (int m=1; m<64; m<<=1) ss += __shfl_xor(ss, m);
  const float sc = rsqrtf(ss*(1.f/DM) + 1e-4f);
  float4 wv = ((const float4*)w)[lane];
  u32 p0 = f2bf(v.x*sc*wv.x) | ((u32)f2bf(v.y*sc*wv.y) << 16);
  u32 p1 = f2bf(v.z*sc*wv.z) | ((u32)f2bf(v.w*sc*wv.w) << 16);
  uint2 pk; pk.x = p0; pk.y = p1;
  *(uint2*)(out + base + lane*4) = pk;
}

// ---------- final layernorm ----------
__global__ __launch_bounds__(256) void k_final_ln(
    const float* __restrict__ x, const float* __restrict__ residual,
    const float* __restrict__ w, const float* __restrict__ bb, float* __restrict__ out)
{
  const int row  = blockIdx.x*4 + (threadIdx.x >> 6);
  const int lane = threadIdx.x & 63;
  const size_t base = (size_t)row*DM;
  float4 v = ((const float4*)(x + base))[lane];
  float4 r = ((const float4*)(residual + base))[lane];
  v.x += r.x; v.y += r.y; v.z += r.z; v.w += r.w;
  float s = v.x + v.y + v.z + v.w;
  #pragma unroll
  for (int m=1; m<64; m<<=1) s += __shfl_xor(s, m);
  const float mu = s*(1.f/DM);
  float4 c; c.x=v.x-mu; c.y=v.y-mu; c.z=v.z-mu; c.w=v.w-mu;
  float ss = c.x*c.x + c.y*c.y + c.z*c.z + c.w*c.w;
  #pragma unroll
  for (int m=1; m<64; m<<=1) ss += __shfl_xor(ss, m);
  const float sc = rsqrtf(ss*(1.f/DM) + 1e-4f);
  float4 wv = ((const float4*)w)[lane];
  float4 bv = ((const float4*)bb)[lane];
  float4 o;
  o.x = c.x*sc*wv.x + bv.x; o.y = c.y*sc*wv.y + bv.y;
  o.z = c.z*sc*wv.z + bv.z; o.w = c.w*sc*wv.w + bv.w;
  ((float4*)(out + base))[lane] = o;
}

// ---------- bf16 MFMA GEMM: C[M,Nc] = A[M,K] @ W[N,K]^T ----------
// BM=128, BK=64, 256 threads (4 waves as 2x2), wave tile 64 x (BN/2)
template<int BN, bool BF16OUT>
__global__ __launch_bounds__(256) void k_gemm_bf(
    const u16* __restrict__ A, const u16* __restrict__ W,
    void* __restrict__ Cv, int Nc, int K)
{
  const int n0 = blockIdx.x * BN;
  const int m0 = blockIdx.y * 128;
  const int tid = threadIdx.x;
  const int w  = tid >> 6, l = tid & 63;
  const int wr = w >> 1, wc = w & 1;
  const int lr = l & 15, kb = l >> 4;
  constexpr int NJ = BN / 32;
  __shared__ uint4 As4[128*8];
  __shared__ uint4 Bs4[BN*8];
  f32x4 acc[4][NJ];
  #pragma unroll
  for (int i=0;i<4;i++)
    #pragma unroll
    for (int j=0;j<NJ;j++)
      acc[i][j] = (f32x4){0.f,0.f,0.f,0.f};
  const int srow = tid >> 3, schunk = tid & 7;
  for (int k0 = 0; k0 < K; k0 += 64){
    #pragma unroll
    for (int i=0;i<4;i++){
      int r = i*32 + srow;
      uint4 v = *(const uint4*)(A + (size_t)(m0 + r)*K + k0 + schunk*8);
      As4[r*8 + (schunk ^ (r & 7))] = v;
    }
    #pragma unroll
    for (int i=0;i<BN/32;i++){
      int r = i*32 + srow;
      uint4 v = *(const uint4*)(W + (size_t)(n0 + r)*K + k0 + schunk*8);
      Bs4[r*8 + (schunk ^ (r & 7))] = v;
    }
    __syncthreads();
    #pragma unroll
    for (int kk=0;kk<2;kk++){
      bf16x8 af[4], bfr[NJ];
      #pragma unroll
      for (int mi=0;mi<4;mi++){
        int r = wr*64 + mi*16 + lr;
        af[mi] = *(const bf16x8*)&As4[r*8 + ((kk*4 + kb) ^ (r & 7))];
      }
      #pragma unroll
      for (int ni=0;ni<NJ;ni++){
        int r = wc*(BN/2) + ni*16 + lr;
        bfr[ni] = *(const bf16x8*)&Bs4[r*8 + ((kk*4 + kb) ^ (r & 7))];
      }
      #pragma unroll
      for (int mi=0;mi<4;mi++)
        #pragma unroll
        for (int ni=0;ni<NJ;ni++)
          acc[mi][ni] = __builtin_amdgcn_mfma_f32_16x16x32_bf16(af[mi], bfr[ni], acc[mi][ni], 0, 0, 0);
    }
    __syncthreads();
  }
  #pragma unroll
  for (int mi=0;mi<4;mi++){
    #pragma unroll
    for (int ni=0;ni<NJ;ni++){
      int col = n0 + wc*(BN/2) + ni*16 + lr;
      if (col < Nc){
        #pragma unroll
        for (int r=0;r<4;r++){
          size_t row = (size_t)(m0 + wr*64 + mi*16 + kb*4 + r);
          if (BF16OUT) ((u16*)Cv)[row*Nc + col] = f2bf(acc[mi][ni][r]);
          else         ((float*)Cv)[row*Nc + col] = acc[mi][ni][r];
        }
      }
    }
  }
}

// ---------- causal depthwise conv1d (k=4) + silu; xz is bf16 stride 1024 ----------
__global__ __launch_bounds__(256) void k_conv1d_silu(
    const u16* __restrict__ xz, const float* __restrict__ cw,
    const float* __restrict__ cb, float* __restrict__ xc, u16* __restrict__ xcb)
{
  const int idx = blockIdx.x*256 + threadIdx.x;   // over Mc*DI
  const int d = idx & (DI-1);
  const int m = idx >> 9;
  const int l = m & (L_SEQ-1);
  const float w0=cw[d*4+0], w1=cw[d*4+1], w2=cw[d*4+2], w3=cw[d*4+3];
  float acc = cb[d];
  if (l >= 3) acc += w0 * bf2f(xz[(size_t)(m-3)*1024 + d]);
  if (l >= 2) acc += w1 * bf2f(xz[(size_t)(m-2)*1024 + d]);
  if (l >= 1) acc += w2 * bf2f(xz[(size_t)(m-1)*1024 + d]);
  acc += w3 * bf2f(xz[(size_t)m*1024 + d]);
  float s = f_silu(acc);
  xc [(size_t)m*DI + d] = s;
  xcb[(size_t)m*DI + d] = f2bf(s);
}

// ---------- dt = softplus(dt_raw @ dtw^T + dtb) ----------
__global__ __launch_bounds__(256) void k_dtproj(
    const float* __restrict__ xdbl, const float* __restrict__ dtw,
    const float* __restrict__ dtb, float* __restrict__ dt)
{
  const int idx = blockIdx.x*256 + threadIdx.x;
  const int d = idx & (DI-1);
  const size_t m = (size_t)(idx >> 9);
  const float* xr = xdbl + m*48;
  const float* wr = dtw + (size_t)d*16;
  float acc = dtb[d];
  #pragma unroll
  for (int k=0;k<16;k++) acc += xr[k]*wr[k];
  dt[(size_t)idx] = f_softplus(acc);
}

// ---------- selective scan; out y -> bf16 ----------
__global__ __launch_bounds__(512) void k_scan(
    const float* __restrict__ xdbl, const float* __restrict__ xc,
    const u16* __restrict__ xz, const float* __restrict__ dtv,
    u16* __restrict__ ybf,
    const float* __restrict__ A_log, const float* __restrict__ Dp)
{
  const int b = blockIdx.x;
  const int d = threadIdx.x;
  const int tid = threadIdx.x;
  __shared__ float BC[2][8][32];
  float Areg[DS];
  bool structured = true;
  #pragma unroll
  for (int n=0;n<DS;n++){
    Areg[n] = -__expf(A_log[(size_t)d*DS + n]);
    structured = structured && (fabsf(Areg[n] + (float)(n+1)) < 1e-4f*(float)(n+1));
  }
  const float Dv = Dp[d];
  float h[DS];
  #pragma unroll
  for (int n=0;n<DS;n++) h[n]=0.f;
  const size_t rowbase = (size_t)b*L_SEQ;
  if (tid < 256) BC[0][tid>>5][tid&31] = xdbl[(rowbase + (tid>>5))*48 + 16 + (tid&31)];
  float dt_n = dtv[rowbase*DI + d];
  float u_n  = xc [rowbase*DI + d];
  float z_n  = bf2f(xz[rowbase*1024 + 512 + d]);
  __syncthreads();
  for (int t8=0; t8<32; ++t8){
    const int cur = t8 & 1;
    if (t8+1 < 32 && tid < 256)
      BC[cur^1][tid>>5][tid&31] = xdbl[(rowbase + (t8+1)*8 + (tid>>5))*48 + 16 + (tid&31)];
    #pragma unroll
    for (int s=0;s<8;s++){
      const int lpos = t8*8 + s;
      const float dt_v = dt_n, u_v = u_n, z_v = z_n;
      if (lpos+1 < L_SEQ){
        dt_n = dtv[(rowbase+lpos+1)*DI + d];
        u_n  = xc [(rowbase+lpos+1)*DI + d];
        z_n  = bf2f(xz[(rowbase+lpos+1)*1024 + 512 + d]);
      }
      const float dtu = dt_v * u_v;
      float y = 0.f;
      if (structured){
        const float p = __expf(-dt_v);
        float pk = 1.f;
        #pragma unroll
        for (int n=0;n<DS;n++){
          pk *= p;
          h[n] = pk*h[n] + dtu*BC[cur][s][n];
          y += h[n]*BC[cur][s][16+n];
        }
      } else {
        #pragma unroll
        for (int n=0;n<DS;n++){
          float dA = __expf(dt_v*Areg[n]);
          h[n] = dA*h[n] + dtu*BC[cur][s][n];
          y += h[n]*BC[cur][s][16+n];
        }
      }
      ybf[(rowbase+lpos)*DI + d] = f2bf((y + u_v*Dv) * f_silu(z_v));
    }
    __syncthreads();
  }
}

// ---------- GLU -> bf16 ----------
__global__ __launch_bounds__(256) void k_glu(
    const float* __restrict__ yg, u16* __restrict__ out)
{
  const int idx = blockIdx.x*256 + threadIdx.x;
  const int j = idx & (MLPH-1);
  const size_t m = (size_t)(idx >> 7);
  float a = yg[m*(2*MLPH) + j];
  float g = yg[m*(2*MLPH) + MLPH + j];
  out[(size_t)idx] = f2bf(a * f_silu(g));
}

// ---------- masked mean pool ----------
__global__ __launch_bounds__(256) void k_pool(
    const float* __restrict__ zf, const int* __restrict__ mask,
    float* __restrict__ pool, int b0)
{
  const int b = blockIdx.x;
  const int d = threadIdx.x;
  __shared__ float mrow[L_SEQ];
  for (int l = d; l < L_SEQ; l += 256) mrow[l] = (float)mask[(size_t)(b0+b)*L_SEQ + l];
  __syncthreads();
  float s = 0.f, ms = 0.f;
  for (int l=0;l<L_SEQ;l++){
    float mv = mrow[l];
    s  += mv * zf[((size_t)b*L_SEQ + l)*DM + d];
    ms += mv;
  }
  pool[(size_t)(b0+b)*DM + d] = s/ms;
}

// ---------- bind head ----------
__global__ __launch_bounds__(64) void k_bind(
    const float* __restrict__ pool, const float* __restrict__ bw,
    const float* __restrict__ bb, float* __restrict__ out)
{
  const int b = blockIdx.x;
  const int lane = threadIdx.x;
  float4 p = ((const float4*)(pool + (size_t)b*DM))[lane];
  #pragma unroll
  for (int j=0;j<3;j++){
    float4 w = ((const float4*)(bw + (size_t)j*DM))[lane];
    float s = p.x*w.x + p.y*w.y + p.z*w.z + p.w*w.w;
    #pragma unroll
    for (int m=1;m<64;m<<=1) s += __shfl_xor(s, m);
    if (lane==0) out[b*3 + j] = f_sigmoid(s + bb[j]);
  }
}

extern "C" void kernel_launch(void* const* d_in, const int* in_sizes, int n_in,
                              void* d_out, int out_size, void* d_ws, size_t ws_size,
                              hipStream_t stream)
{
  const int*   tok       = (const int*)  d_in[0];
  const int*   mask      = (const int*)  d_in[1];
  const float* emb       = (const float*)d_in[2];
  const float* conv_w    = (const float*)d_in[3];
  const float* bn_gamma  = (const float*)d_in[4];
  const float* bn_beta   = (const float*)d_in[5];
  const float* in_proj_w = (const float*)d_in[6];
  const float* conv1d_w  = (const float*)d_in[7];
  const float* conv1d_b  = (const float*)d_in[8];
  const float* x_proj_w  = (const float*)d_in[9];
  const float* dt_proj_w = (const float*)d_in[10];
  const float* dt_proj_b = (const float*)d_in[11];
  const float* A_log     = (const float*)d_in[12];
  const float* Dp        = (const float*)d_in[13];
  const float* out_proj_w= (const float*)d_in[14];
  const float* norm1_w   = (const float*)d_in[15];
  const float* norm2_w   = (const float*)d_in[16];
  const float* fc1_w     = (const float*)d_in[17];
  const float* fc2_w     = (const float*)d_in[18];
  const float* normf_w   = (const float*)d_in[19];
  const float* normf_b   = (const float*)d_in[20];
  const float* bind_w    = (const float*)d_in[21];
  const float* bind_b    = (const float*)d_in[22];
  float* outp = (float*)d_out;

  // ---- workspace layout (bytes) ----
  char* base = (char*)d_ws;
  size_t off = 0;
  const int NIN = NL*2*DI*DM, NOUT = NL*DM*DI, NF1 = NL*2*MLPH*DM, NF2 = NL*DM*MLPH, NXP = NL*64*DI;
  u16* w_in  = (u16*)(base + off); off += (size_t)NIN*2;
  u16* w_out = (u16*)(base + off); off += (size_t)NOUT*2;
  u16* w_f1  = (u16*)(base + off); off += (size_t)NF1*2;
  u16* w_f2  = (u16*)(base + off); off += (size_t)NF2*2;
  u16* w_xp  = (u16*)(base + off); off += (size_t)NXP*2;
  float* pool = (float*)(base + off); off += (size_t)B_TOT*DM*4;
  const size_t fixed = off;

  // per-position bytes: f32(256+256+512+48+256+256)=1584*4 + u16(1024+512+512+256+128)=2432*2
  const size_t perRow = 1584*4 + 2432*2;
  int Bc = B_TOT;
  while (Bc > 1 && fixed + (size_t)Bc*L_SEQ*perRow > ws_size) Bc >>= 1;
  const int Mc = Bc * L_SEQ;

  float* residual = (float*)(base + off); off += (size_t)Mc*DM*4;
  float* hidden   = (float*)(base + off); off += (size_t)Mc*DM*4;
  float* xc       = (float*)(base + off); off += (size_t)Mc*DI*4;
  float* dty      = (float*)(base + off); off += (size_t)Mc*DI*4;
  float* xdbl     = (float*)(base + off); off += (size_t)Mc*48*4;
  float* yg       = (float*)(base + off); off += (size_t)Mc*DM*4;
  float* mamba    = (float*)(base + off); off += (size_t)Mc*DM*4;
  u16*   xz       = (u16*)(base + off);   off += (size_t)Mc*1024*2;
  u16*   xcb      = (u16*)(base + off);   off += (size_t)Mc*DI*2;
  u16*   ybf      = (u16*)(base + off);   off += (size_t)Mc*DI*2;
  u16*   hsbf     = (u16*)(base + off);   off += (size_t)Mc*DM*2;
  u16*   glubf    = (u16*)(base + off);   off += (size_t)Mc*MLPH*2;
  float* zf       = xc;  // reuse after layers

  // ---- weight conversion (cheap, every launch: deterministic) ----
  k_cvt<<<(NIN +255)/256, 256, 0, stream>>>(in_proj_w,  w_in,  NIN);
  k_cvt<<<(NOUT+255)/256, 256, 0, stream>>>(out_proj_w, w_out, NOUT);
  k_cvt<<<(NF1 +255)/256, 256, 0, stream>>>(fc1_w,      w_f1,  NF1);
  k_cvt<<<(NF2 +255)/256, 256, 0, stream>>>(fc2_w,      w_f2,  NF2);
  k_cvt_xproj<<<(NXP+255)/256, 256, 0, stream>>>(x_proj_w, w_xp);

  const int nchunks = B_TOT / Bc;
  for (int c = 0; c < nchunks; ++c){
    const int b0 = c * Bc;
    k_embed_conv<<<dim3(L_SEQ/16, Bc), 256, 0, stream>>>(
        tok + (size_t)b0*L_SEQ, emb, conv_w, bn_gamma, bn_beta, hidden);

    for (int i = 0; i < NL; ++i){
      const u16*  inw  = w_in  + (size_t)i*(2*DI)*DM;
      const float* cw  = conv1d_w  + (size_t)i*DI*4;
      const float* cb  = conv1d_b  + (size_t)i*DI;
      const u16*  xpw  = w_xp  + (size_t)i*64*DI;
      const float* dtw = dt_proj_w + (size_t)i*DI*16;
      const float* dtb = dt_proj_b + (size_t)i*DI;
      const float* Alg = A_log     + (size_t)i*DI*DS;
      const float* Dpt = Dp        + (size_t)i*DI;
      const u16*  outw = w_out + (size_t)i*DM*DI;
      const float* n1w = norm1_w   + (size_t)i*DM;
      const float* n2w = norm2_w   + (size_t)i*DM;
      const u16*  f1w  = w_f1  + (size_t)i*(2*MLPH)*DM;
      const u16*  f2w  = w_f2  + (size_t)i*DM*MLPH;

      if (i == 0)
        k_add_rmsnorm<true ><<<Mc/4, 256, 0, stream>>>(hidden, residual, n1w, hsbf);
      else
        k_add_rmsnorm<false><<<Mc/4, 256, 0, stream>>>(hidden, residual, n1w, hsbf);

      k_gemm_bf<128,true ><<<dim3((2*DI)/128, Mc/128), 256, 0, stream>>>(hsbf, inw, xz, 2*DI, DM);
      k_conv1d_silu<<<(Mc*DI)/256, 256, 0, stream>>>(xz, cw, cb, xc, xcb);
      k_gemm_bf<64, false><<<dim3(1, Mc/128), 256, 0, stream>>>(xcb, xpw, xdbl, 48, DI);
      k_dtproj<<<(Mc*DI)/256, 256, 0, stream>>>(xdbl, dtw, dtb, dty);
      k_scan<<<Bc, 512, 0, stream>>>(xdbl, xc, xz, dty, ybf, Alg, Dpt);
      k_gemm_bf<128,false><<<dim3(DM/128, Mc/128), 256, 0, stream>>>(ybf, outw, mamba, DM, DI);
      k_add_rmsnorm<false><<<Mc/4, 256, 0, stream>>>(mamba, residual, n2w, hsbf);
      k_gemm_bf<128,false><<<dim3((2*MLPH)/128, Mc/128), 256, 0, stream>>>(hsbf, f1w, yg, 2*MLPH, DM);
      k_glu<<<(Mc*MLPH)/256, 256, 0, stream>>>(yg, glubf);
      k_gemm_bf<128,false><<<dim3(DM/128, Mc/128), 256, 0, stream>>>(glubf, f2w, hidden, DM, MLPH);
    }

    k_final_ln<<<Mc/4, 256, 0, stream>>>(hidden, residual, normf_w, normf_b, zf);
    k_pool<<<Bc, 256, 0, stream>>>(zf, mask, pool, b0);
  }
  k_bind<<<B_TOT, 64, 0, stream>>>(pool, bind_w, bind_b, outp);
}

// Round 3
// 4768.100 us; speedup vs baseline: 3.3256x; 1.4906x over previous
//
#include <hip/hip_runtime.h>
#include <math.h>

#define B_TOT 256
#define L_SEQ 256
#define DM 256
#define DI 512
#define DS 16
#define NL 6
#define MLPH 128
#define ED 64

typedef unsigned short u16;
typedef unsigned int   u32;
using bf16x8 = __attribute__((ext_vector_type(8))) short;
using f32x4  = __attribute__((ext_vector_type(4))) float;

__device__ __forceinline__ float f_sigmoid(float x){ return 1.f/(1.f+__expf(-x)); }
__device__ __forceinline__ float f_silu(float x){ return x/(1.f+__expf(-x)); }
__device__ __forceinline__ u16 f2bf(float x){
  union { float f; u32 u; } v; v.f = x;
  u32 r = v.u + 0x7fffu + ((v.u >> 16) & 1u);
  return (u16)(r >> 16);
}
__device__ __forceinline__ float bf2f(u16 h){
  union { u32 u; float f; } v; v.u = ((u32)h) << 16; return v.f;
}

// ---------- weight conversion ----------
__global__ __launch_bounds__(256) void k_cvt(const float* __restrict__ s, u16* __restrict__ d, int n){
  int i = blockIdx.x*256 + threadIdx.x;
  if (i < n) d[i] = f2bf(s[i]);
}
__global__ __launch_bounds__(256) void k_cvt_xproj(const float* __restrict__ s, u16* __restrict__ d){
  int i = blockIdx.x*256 + threadIdx.x;      // over NL*64*512
  int k = i & 511; int n = (i>>9) & 63; int l = i >> 15;
  d[i] = (n < 48) ? f2bf(s[((size_t)l*48 + n)*512 + k]) : (u16)0;
}

// ---------- embedding + conv(k=3) + affine + relu -> residual ----------
__global__ __launch_bounds__(256) void k_embed_conv(
    const int* __restrict__ tok, const float* __restrict__ emb,
    const float* __restrict__ cw, const float* __restrict__ gamma,
    const float* __restrict__ beta, float* __restrict__ out)
{
  const int b  = blockIdx.y;
  const int lt = blockIdx.x;
  const int tid = threadIdx.x;
  __shared__ float xs[18][ED];
  for (int idx = tid; idx < 18*ED; idx += 256){
    int t = idx / ED, i = idx - t*ED;
    int l = lt*16 + t - 1;
    float v = 0.f;
    if (l >= 0 && l < L_SEQ) v = emb[tok[b*L_SEQ + l]*ED + i];
    xs[t][i] = v;
  }
  __syncthreads();
  const float g  = gamma[tid] * rsqrtf(1.001f);
  const float bt = beta[tid];
  const float* w = cw + (size_t)tid*(ED*3);
  float acc[16];
  #pragma unroll
  for (int t=0;t<16;t++) acc[t]=0.f;
  for (int i=0;i<ED;i++){
    float w0 = w[i*3+0], w1 = w[i*3+1], w2 = w[i*3+2];
    #pragma unroll
    for (int t=0;t<16;t++)
      acc[t] += xs[t][i]*w0 + xs[t+1][i]*w1 + xs[t+2][i]*w2;
  }
  #pragma unroll
  for (int t=0;t<16;t++){
    float v = acc[t]*g + bt;
    out[((size_t)(b*L_SEQ + lt*16 + t))*DM + tid] = fmaxf(v, 0.f);
  }
}

// ---------- rmsnorm of residual -> bf16 (first layer only) ----------
__global__ __launch_bounds__(256) void k_rms_first(
    const float* __restrict__ residual, const float* __restrict__ w, u16* __restrict__ out)
{
  const int row  = blockIdx.x*4 + (threadIdx.x >> 6);
  const int lane = threadIdx.x & 63;
  const size_t base = (size_t)row*DM;
  float4 v = ((const float4*)(residual + base))[lane];
  float ss = v.x*v.x + v.y*v.y + v.z*v.z + v.w*v.w;
  #pragma unroll
  for (int m=1; m<64; m<<=1) ss += __shfl_xor(ss, m);
  const float sc = rsqrtf(ss*(1.f/DM) + 1e-4f);
  float4 wv = ((const float4*)w)[lane];
  u32 p0 = f2bf(v.x*sc*wv.x) | ((u32)f2bf(v.y*sc*wv.y) << 16);
  u32 p1 = f2bf(v.z*sc*wv.z) | ((u32)f2bf(v.w*sc*wv.w) << 16);
  uint2 pk; pk.x = p0; pk.y = p1;
  *(uint2*)(out + base + lane*4) = pk;
}

// ---------- final layernorm (input: residual, already hidden+residual) ----------
__global__ __launch_bounds__(256) void k_final_ln(
    const float* __restrict__ x,
    const float* __restrict__ w, const float* __restrict__ bb, float* __restrict__ out)
{
  const int row  = blockIdx.x*4 + (threadIdx.x >> 6);
  const int lane = threadIdx.x & 63;
  const size_t base = (size_t)row*DM;
  float4 v = ((const float4*)(x + base))[lane];
  float s = v.x + v.y + v.z + v.w;
  #pragma unroll
  for (int m=1; m<64; m<<=1) s += __shfl_xor(s, m);
  const float mu = s*(1.f/DM);
  float4 c; c.x=v.x-mu; c.y=v.y-mu; c.z=v.z-mu; c.w=v.w-mu;
  float ss = c.x*c.x + c.y*c.y + c.z*c.z + c.w*c.w;
  #pragma unroll
  for (int m=1; m<64; m<<=1) ss += __shfl_xor(ss, m);
  const float sc = rsqrtf(ss*(1.f/DM) + 1e-4f);
  float4 wv = ((const float4*)w)[lane];
  float4 bv = ((const float4*)bb)[lane];
  float4 o;
  o.x = c.x*sc*wv.x + bv.x; o.y = c.y*sc*wv.y + bv.y;
  o.z = c.z*sc*wv.z + bv.z; o.w = c.w*sc*wv.w + bv.w;
  ((float4*)(out + base))[lane] = o;
}

// ---------- bf16 MFMA GEMM (4 waves): C[M,Nc] = A[M,K] @ W[N,K]^T ----------
template<int BN, bool BF16OUT>
__global__ __launch_bounds__(256) void k_gemm_bf(
    const u16* __restrict__ A, const u16* __restrict__ W,
    void* __restrict__ Cv, int Nc, int K)
{
  const int n0 = blockIdx.x * BN;
  const int m0 = blockIdx.y * 128;
  const int tid = threadIdx.x;
  const int w  = tid >> 6, l = tid & 63;
  const int wr = w >> 1, wc = w & 1;
  const int lr = l & 15, kb = l >> 4;
  constexpr int NJ = BN / 32;
  __shared__ uint4 As4[128*8];
  __shared__ uint4 Bs4[BN*8];
  f32x4 acc[4][NJ];
  #pragma unroll
  for (int i=0;i<4;i++)
    #pragma unroll
    for (int j=0;j<NJ;j++)
      acc[i][j] = (f32x4){0.f,0.f,0.f,0.f};
  const int srow = tid >> 3, schunk = tid & 7;
  for (int k0 = 0; k0 < K; k0 += 64){
    #pragma unroll
    for (int i=0;i<4;i++){
      int r = i*32 + srow;
      uint4 v = *(const uint4*)(A + (size_t)(m0 + r)*K + k0 + schunk*8);
      As4[r*8 + (schunk ^ (r & 7))] = v;
    }
    #pragma unroll
    for (int i=0;i<BN/32;i++){
      int r = i*32 + srow;
      uint4 v = *(const uint4*)(W + (size_t)(n0 + r)*K + k0 + schunk*8);
      Bs4[r*8 + (schunk ^ (r & 7))] = v;
    }
    __syncthreads();
    #pragma unroll
    for (int kk=0;kk<2;kk++){
      bf16x8 af[4], bfr[NJ];
      #pragma unroll
      for (int mi=0;mi<4;mi++){
        int r = wr*64 + mi*16 + lr;
        af[mi] = *(const bf16x8*)&As4[r*8 + ((kk*4 + kb) ^ (r & 7))];
      }
      #pragma unroll
      for (int ni=0;ni<NJ;ni++){
        int r = wc*(BN/2) + ni*16 + lr;
        bfr[ni] = *(const bf16x8*)&Bs4[r*8 + ((kk*4 + kb) ^ (r & 7))];
      }
      #pragma unroll
      for (int mi=0;mi<4;mi++)
        #pragma unroll
        for (int ni=0;ni<NJ;ni++)
          acc[mi][ni] = __builtin_amdgcn_mfma_f32_16x16x32_bf16(af[mi], bfr[ni], acc[mi][ni], 0, 0, 0);
    }
    __syncthreads();
  }
  #pragma unroll
  for (int mi=0;mi<4;mi++){
    #pragma unroll
    for (int ni=0;ni<NJ;ni++){
      int col = n0 + wc*(BN/2) + ni*16 + lr;
      if (col < Nc){
        #pragma unroll
        for (int r=0;r<4;r++){
          size_t row = (size_t)(m0 + wr*64 + mi*16 + kb*4 + r);
          if (BF16OUT) ((u16*)Cv)[row*Nc + col] = f2bf(acc[mi][ni][r]);
          else         ((float*)Cv)[row*Nc + col] = acc[mi][ni][r];
        }
      }
    }
  }
}

// ---------- 8-wave GEMM (N=256) + residual add + rmsnorm fused ----------
// C = A[M,K] @ W[256,K]^T ; residual += C ; hs = rms(residual)*nw (bf16)
template<bool WRITE_HS>
__global__ __launch_bounds__(512) void k_gemm_rms(
    const u16* __restrict__ A, const u16* __restrict__ W,
    float* __restrict__ residual, const float* __restrict__ nw,
    u16* __restrict__ hs, int K)
{
  const int m0 = blockIdx.x * 128;
  const int tid = threadIdx.x;
  const int w = tid >> 6, l = tid & 63;
  const int wr = w >> 1, wc = w & 1;          // 4 row-groups x 2 col-groups
  const int lr = l & 15, kb = l >> 4;
  __shared__ uint4 As4[128*8];
  __shared__ uint4 Bs4[256*8];
  __shared__ float red[128][2];
  f32x4 acc[2][8];
  #pragma unroll
  for (int i=0;i<2;i++)
    #pragma unroll
    for (int j=0;j<8;j++) acc[i][j] = (f32x4){0.f,0.f,0.f,0.f};
  const int srow = tid >> 3, schunk = tid & 7;   // srow 0..63
  for (int k0 = 0; k0 < K; k0 += 64){
    #pragma unroll
    for (int i=0;i<2;i++){
      int r = i*64 + srow;
      uint4 v = *(const uint4*)(A + (size_t)(m0 + r)*K + k0 + schunk*8);
      As4[r*8 + (schunk ^ (r & 7))] = v;
    }
    #pragma unroll
    for (int i=0;i<4;i++){
      int r = i*64 + srow;
      uint4 v = *(const uint4*)(W + (size_t)r*K + k0 + schunk*8);
      Bs4[r*8 + (schunk ^ (r & 7))] = v;
    }
    __syncthreads();
    #pragma unroll
    for (int kk=0;kk<2;kk++){
      bf16x8 af[2], bfr[8];
      #pragma unroll
      for (int mi=0;mi<2;mi++){
        int r = wr*32 + mi*16 + lr;
        af[mi] = *(const bf16x8*)&As4[r*8 + ((kk*4 + kb) ^ (r & 7))];
      }
      #pragma unroll
      for (int ni=0;ni<8;ni++){
        int r = wc*128 + ni*16 + lr;
        bfr[ni] = *(const bf16x8*)&Bs4[r*8 + ((kk*4 + kb) ^ (r & 7))];
      }
      #pragma unroll
      for (int mi=0;mi<2;mi++)
        #pragma unroll
        for (int ni=0;ni<8;ni++)
          acc[mi][ni] = __builtin_amdgcn_mfma_f32_16x16x32_bf16(af[mi], bfr[ni], acc[mi][ni], 0, 0, 0);
    }
    __syncthreads();
  }
  // epilogue: add residual, rms
  float p[2][4];
  #pragma unroll
  for (int mi=0;mi<2;mi++)
    #pragma unroll
    for (int r=0;r<4;r++) p[mi][r] = 0.f;
  #pragma unroll
  for (int mi=0;mi<2;mi++){
    #pragma unroll
    for (int ni=0;ni<8;ni++){
      int col = wc*128 + ni*16 + lr;
      #pragma unroll
      for (int r=0;r<4;r++){
        int row = wr*32 + mi*16 + kb*4 + r;
        float v = acc[mi][ni][r] + residual[(size_t)(m0+row)*DM + col];
        acc[mi][ni][r] = v;
        p[mi][r] += v*v;
      }
    }
  }
  #pragma unroll
  for (int mi=0;mi<2;mi++)
    #pragma unroll
    for (int r=0;r<4;r++){
      float s = p[mi][r];
      s += __shfl_xor(s, 1); s += __shfl_xor(s, 2);
      s += __shfl_xor(s, 4); s += __shfl_xor(s, 8);
      p[mi][r] = s;
    }
  if (lr == 0){
    #pragma unroll
    for (int mi=0;mi<2;mi++)
      #pragma unroll
      for (int r=0;r<4;r++)
        red[wr*32 + mi*16 + kb*4 + r][wc] = p[mi][r];
  }
  __syncthreads();
  #pragma unroll
  for (int mi=0;mi<2;mi++){
    float scm[4];
    #pragma unroll
    for (int r=0;r<4;r++){
      int row = wr*32 + mi*16 + kb*4 + r;
      scm[r] = rsqrtf((red[row][0]+red[row][1])*(1.f/DM) + 1e-4f);
    }
    #pragma unroll
    for (int ni=0;ni<8;ni++){
      int col = wc*128 + ni*16 + lr;
      float wn = WRITE_HS ? nw[col] : 0.f;
      #pragma unroll
      for (int r=0;r<4;r++){
        int row = wr*32 + mi*16 + kb*4 + r;
        float v = acc[mi][ni][r];
        residual[(size_t)(m0+row)*DM + col] = v;
        if (WRITE_HS) hs[(size_t)(m0+row)*DM + col] = f2bf(v*scm[r]*wn);
      }
    }
  }
}

// ---------- 8-wave fc1 (N=256) + GLU fused: out = y * silu(g) (bf16) ----------
__global__ __launch_bounds__(512) void k_fc1_glu(
    const u16* __restrict__ A, const u16* __restrict__ W, u16* __restrict__ out)
{
  const int K = DM;            // 256
  const int m0 = blockIdx.x * 128;
  const int tid = threadIdx.x;
  const int w = tid >> 6, l = tid & 63;
  const int wr = w >> 1, wc = w & 1;
  const int lr = l & 15, kb = l >> 4;
  __shared__ uint4 As4[128*8];
  __shared__ uint4 Bs4[256*8];
  f32x4 acc[2][8];
  #pragma unroll
  for (int i=0;i<2;i++)
    #pragma unroll
    for (int j=0;j<8;j++) acc[i][j] = (f32x4){0.f,0.f,0.f,0.f};
  const int srow = tid >> 3, schunk = tid & 7;
  for (int k0 = 0; k0 < K; k0 += 64){
    #pragma unroll
    for (int i=0;i<2;i++){
      int r = i*64 + srow;
      uint4 v = *(const uint4*)(A + (size_t)(m0 + r)*K + k0 + schunk*8);
      As4[r*8 + (schunk ^ (r & 7))] = v;
    }
    #pragma unroll
    for (int i=0;i<4;i++){
      int r = i*64 + srow;
      uint4 v = *(const uint4*)(W + (size_t)r*K + k0 + schunk*8);
      Bs4[r*8 + (schunk ^ (r & 7))] = v;
    }
    __syncthreads();
    #pragma unroll
    for (int kk=0;kk<2;kk++){
      bf16x8 af[2], bfr[8];
      #pragma unroll
      for (int mi=0;mi<2;mi++){
        int r = wr*32 + mi*16 + lr;
        af[mi] = *(const bf16x8*)&As4[r*8 + ((kk*4 + kb) ^ (r & 7))];
      }
      #pragma unroll
      for (int ni=0;ni<8;ni++){
        // ni<4 -> y rows (wc*64+ni*16), ni>=4 -> g rows (128+wc*64+(ni-4)*16)
        int r = (ni < 4) ? (wc*64 + ni*16 + lr) : (128 + wc*64 + (ni-4)*16 + lr);
        bfr[ni] = *(const bf16x8*)&Bs4[r*8 + ((kk*4 + kb) ^ (r & 7))];
      }
      #pragma unroll
      for (int mi=0;mi<2;mi++)
        #pragma unroll
        for (int ni=0;ni<8;ni++)
          acc[mi][ni] = __builtin_amdgcn_mfma_f32_16x16x32_bf16(af[mi], bfr[ni], acc[mi][ni], 0, 0, 0);
    }
    __syncthreads();
  }
  #pragma unroll
  for (int mi=0;mi<2;mi++){
    #pragma unroll
    for (int ni=0;ni<4;ni++){
      int jcol = wc*64 + ni*16 + lr;
      #pragma unroll
      for (int r=0;r<4;r++){
        int row = wr*32 + mi*16 + kb*4 + r;
        float y = acc[mi][ni][r];
        float g = acc[mi][ni+4][r];
        out[(size_t)(m0+row)*MLPH + jcol] = f2bf(y * f_silu(g));
      }
    }
  }
}

// ---------- causal depthwise conv1d (k=4) + silu -> bf16 only ----------
__global__ __launch_bounds__(256) void k_conv1d_silu(
    const u16* __restrict__ xz, const float* __restrict__ cw,
    const float* __restrict__ cb, u16* __restrict__ xcb)
{
  const int idx = blockIdx.x*256 + threadIdx.x;   // over Mc*DI
  const int d = idx & (DI-1);
  const int m = idx >> 9;
  const int l = m & (L_SEQ-1);
  const float w0=cw[d*4+0], w1=cw[d*4+1], w2=cw[d*4+2], w3=cw[d*4+3];
  float acc = cb[d];
  if (l >= 3) acc += w0 * bf2f(xz[(size_t)(m-3)*1024 + d]);
  if (l >= 2) acc += w1 * bf2f(xz[(size_t)(m-2)*1024 + d]);
  if (l >= 1) acc += w2 * bf2f(xz[(size_t)(m-1)*1024 + d]);
  acc += w3 * bf2f(xz[(size_t)m*1024 + d]);
  xcb[(size_t)m*DI + d] = f2bf(f_silu(acc));
}

// ---------- selective scan with fused dt-proj; y -> bf16 ----------
// grid (Bc, 2), 256 threads; block handles d = blockIdx.y*256 + tid
__global__ __launch_bounds__(256) void k_scan(
    const float* __restrict__ xdbl, const u16* __restrict__ xcb,
    const u16* __restrict__ xz, u16* __restrict__ ybf,
    const float* __restrict__ A_log, const float* __restrict__ Dp,
    const float* __restrict__ dtw, const float* __restrict__ dtb)
{
  const int b = blockIdx.x;
  const int tid = threadIdx.x;
  const int d = blockIdx.y*256 + tid;
  __shared__ float BD[2][8][48];
  float dtw_r[16];
  #pragma unroll
  for (int k=0;k<16;k++) dtw_r[k] = dtw[(size_t)d*16 + k];
  const float dtb_r = dtb[d];
  float Areg[DS];
  bool structured = true;
  #pragma unroll
  for (int n=0;n<DS;n++){
    Areg[n] = -__expf(A_log[(size_t)d*DS + n]);
    structured = structured && (fabsf(Areg[n] + (float)(n+1)) < 1e-4f*(float)(n+1));
  }
  const float Dv = Dp[d];
  float h[DS];
  #pragma unroll
  for (int n=0;n<DS;n++) h[n]=0.f;
  const size_t rowbase = (size_t)b*L_SEQ;
  for (int idx=tid; idx<384; idx+=256)
    BD[0][idx/48][idx%48] = xdbl[(rowbase + idx/48)*48 + idx%48];
  float u_n = bf2f(xcb[rowbase*DI + d]);
  float z_n = bf2f(xz [rowbase*1024 + 512 + d]);
  __syncthreads();
  for (int t8=0; t8<32; ++t8){
    const int cur = t8 & 1;
    if (t8+1 < 32)
      for (int idx=tid; idx<384; idx+=256)
        BD[cur^1][idx/48][idx%48] = xdbl[(rowbase + (t8+1)*8 + idx/48)*48 + idx%48];
    #pragma unroll
    for (int s=0;s<8;s++){
      const int lpos = t8*8 + s;
      const float u_v = u_n, z_v = z_n;
      if (lpos+1 < L_SEQ){
        u_n = bf2f(xcb[(rowbase+lpos+1)*DI + d]);
        z_n = bf2f(xz [(rowbase+lpos+1)*1024 + 512 + d]);
      }
      // dt projection in-register
      float x = dtb_r;
      #pragma unroll
      for (int k=0;k<16;k++) x += BD[cur][s][k]*dtw_r[k];
      const float ex = __expf(x);
      const float dt_v = (x > 20.f) ? x : log1pf(ex);
      const float dtu = dt_v * u_v;
      float y = 0.f;
      if (structured){
        const float p = 1.f/(1.f + ex);     // exp(-softplus(x))
        float pk = 1.f;
        #pragma unroll
        for (int n=0;n<DS;n++){
          pk *= p;
          h[n] = pk*h[n] + dtu*BD[cur][s][16+n];
          y += h[n]*BD[cur][s][32+n];
        }
      } else {
        #pragma unroll
        for (int n=0;n<DS;n++){
          float dA = __expf(dt_v*Areg[n]);
          h[n] = dA*h[n] + dtu*BD[cur][s][16+n];
          y += h[n]*BD[cur][s][32+n];
        }
      }
      ybf[(rowbase+lpos)*DI + d] = f2bf((y + u_v*Dv) * f_silu(z_v));
    }
    __syncthreads();
  }
}

// ---------- masked mean pool ----------
__global__ __launch_bounds__(256) void k_pool(
    const float* __restrict__ zf, const int* __restrict__ mask,
    float* __restrict__ pool, int b0)
{
  const int b = blockIdx.x;
  const int d = threadIdx.x;
  __shared__ float mrow[L_SEQ];
  for (int l = d; l < L_SEQ; l += 256) mrow[l] = (float)mask[(size_t)(b0+b)*L_SEQ + l];
  __syncthreads();
  float s = 0.f, ms = 0.f;
  for (int l=0;l<L_SEQ;l++){
    float mv = mrow[l];
    s  += mv * zf[((size_t)b*L_SEQ + l)*DM + d];
    ms += mv;
  }
  pool[(size_t)(b0+b)*DM + d] = s/ms;
}

// ---------- bind head ----------
__global__ __launch_bounds__(64) void k_bind(
    const float* __restrict__ pool, const float* __restrict__ bw,
    const float* __restrict__ bb, float* __restrict__ out)
{
  const int b = blockIdx.x;
  const int lane = threadIdx.x;
  float4 p = ((const float4*)(pool + (size_t)b*DM))[lane];
  #pragma unroll
  for (int j=0;j<3;j++){
    float4 w = ((const float4*)(bw + (size_t)j*DM))[lane];
    float s = p.x*w.x + p.y*w.y + p.z*w.z + p.w*w.w;
    #pragma unroll
    for (int m=1;m<64;m<<=1) s += __shfl_xor(s, m);
    if (lane==0) out[b*3 + j] = f_sigmoid(s + bb[j]);
  }
}

extern "C" void kernel_launch(void* const* d_in, const int* in_sizes, int n_in,
                              void* d_out, int out_size, void* d_ws, size_t ws_size,
                              hipStream_t stream)
{
  const int*   tok       = (const int*)  d_in[0];
  const int*   mask      = (const int*)  d_in[1];
  const float* emb       = (const float*)d_in[2];
  const float* conv_w    = (const float*)d_in[3];
  const float* bn_gamma  = (const float*)d_in[4];
  const float* bn_beta   = (const float*)d_in[5];
  const float* in_proj_w = (const float*)d_in[6];
  const float* conv1d_w  = (const float*)d_in[7];
  const float* conv1d_b  = (const float*)d_in[8];
  const float* x_proj_w  = (const float*)d_in[9];
  const float* dt_proj_w = (const float*)d_in[10];
  const float* dt_proj_b = (const float*)d_in[11];
  const float* A_log     = (const float*)d_in[12];
  const float* Dp        = (const float*)d_in[13];
  const float* out_proj_w= (const float*)d_in[14];
  const float* norm1_w   = (const float*)d_in[15];
  const float* norm2_w   = (const float*)d_in[16];
  const float* fc1_w     = (const float*)d_in[17];
  const float* fc2_w     = (const float*)d_in[18];
  const float* normf_w   = (const float*)d_in[19];
  const float* normf_b   = (const float*)d_in[20];
  const float* bind_w    = (const float*)d_in[21];
  const float* bind_b    = (const float*)d_in[22];
  float* outp = (float*)d_out;

  char* base = (char*)d_ws;
  size_t off = 0;
  const int NIN = NL*2*DI*DM, NOUT = NL*DM*DI, NF1 = NL*2*MLPH*DM, NF2 = NL*DM*MLPH, NXP = NL*64*DI;
  u16* w_in  = (u16*)(base + off); off += (size_t)NIN*2;
  u16* w_out = (u16*)(base + off); off += (size_t)NOUT*2;
  u16* w_f1  = (u16*)(base + off); off += (size_t)NF1*2;
  u16* w_f2  = (u16*)(base + off); off += (size_t)NF2*2;
  u16* w_xp  = (u16*)(base + off); off += (size_t)NXP*2;
  float* pool = (float*)(base + off); off += (size_t)B_TOT*DM*4;
  const size_t fixed = off;

  // per-position bytes: f32(256+48)=1216 + u16(1024+512+512+256+128)=4864
  const size_t perRow = 1216 + 4864;
  int Bc = B_TOT;
  while (Bc > 1 && fixed + (size_t)Bc*L_SEQ*perRow > ws_size) Bc >>= 1;
  const int Mc = Bc * L_SEQ;

  float* residual = (float*)(base + off); off += (size_t)Mc*DM*4;
  float* xdbl     = (float*)(base + off); off += (size_t)Mc*48*4;
  u16*   xz       = (u16*)(base + off);   off += (size_t)Mc*1024*2;
  u16*   xcb      = (u16*)(base + off);   off += (size_t)Mc*DI*2;
  u16*   ybf      = (u16*)(base + off);   off += (size_t)Mc*DI*2;
  u16*   hsbf     = (u16*)(base + off);   off += (size_t)Mc*DM*2;
  u16*   glubf    = (u16*)(base + off);   off += (size_t)Mc*MLPH*2;
  float* zf       = (float*)xz;           // reuse xz space after layers

  k_cvt<<<(NIN +255)/256, 256, 0, stream>>>(in_proj_w,  w_in,  NIN);
  k_cvt<<<(NOUT+255)/256, 256, 0, stream>>>(out_proj_w, w_out, NOUT);
  k_cvt<<<(NF1 +255)/256, 256, 0, stream>>>(fc1_w,      w_f1,  NF1);
  k_cvt<<<(NF2 +255)/256, 256, 0, stream>>>(fc2_w,      w_f2,  NF2);
  k_cvt_xproj<<<(NXP+255)/256, 256, 0, stream>>>(x_proj_w, w_xp);

  const int nchunks = B_TOT / Bc;
  for (int c = 0; c < nchunks; ++c){
    const int b0 = c * Bc;
    k_embed_conv<<<dim3(L_SEQ/16, Bc), 256, 0, stream>>>(
        tok + (size_t)b0*L_SEQ, emb, conv_w, bn_gamma, bn_beta, residual);
    k_rms_first<<<Mc/4, 256, 0, stream>>>(residual, norm1_w, hsbf);

    for (int i = 0; i < NL; ++i){
      const u16*  inw  = w_in  + (size_t)i*(2*DI)*DM;
      const float* cw  = conv1d_w  + (size_t)i*DI*4;
      const float* cb  = conv1d_b  + (size_t)i*DI;
      const u16*  xpw  = w_xp  + (size_t)i*64*DI;
      const float* dtw = dt_proj_w + (size_t)i*DI*16;
      const float* dtb = dt_proj_b + (size_t)i*DI;
      const float* Alg = A_log     + (size_t)i*DI*DS;
      const float* Dpt = Dp        + (size_t)i*DI;
      const u16*  outw = w_out + (size_t)i*DM*DI;
      const float* n2w = norm2_w   + (size_t)i*DM;
      const u16*  f1w  = w_f1  + (size_t)i*(2*MLPH)*DM;
      const u16*  f2w  = w_f2  + (size_t)i*DM*MLPH;

      k_gemm_bf<128,true ><<<dim3((2*DI)/128, Mc/128), 256, 0, stream>>>(hsbf, inw, xz, 2*DI, DM);
      k_conv1d_silu<<<(Mc*DI)/256, 256, 0, stream>>>(xz, cw, cb, xcb);
      k_gemm_bf<64, false><<<dim3(1, Mc/128), 256, 0, stream>>>(xcb, xpw, xdbl, 48, DI);
      k_scan<<<dim3(Bc,2), 256, 0, stream>>>(xdbl, xcb, xz, ybf, Alg, Dpt, dtw, dtb);
      k_gemm_rms<true><<<Mc/128, 512, 0, stream>>>(ybf, outw, residual, n2w, hsbf, DI);
      k_fc1_glu<<<Mc/128, 512, 0, stream>>>(hsbf, f1w, glubf);
      if (i < NL-1)
        k_gemm_rms<true ><<<Mc/128, 512, 0, stream>>>(glubf, f2w, residual,
                                                      norm1_w + (size_t)(i+1)*DM, hsbf, MLPH);
      else
        k_gemm_rms<false><<<Mc/128, 512, 0, stream>>>(glubf, f2w, residual,
                                                      nullptr, nullptr, MLPH);
    }

    k_final_ln<<<Mc/4, 256, 0, stream>>>(residual, normf_w, normf_b, zf);
    k_pool<<<Bc, 256, 0, stream>>>(zf, mask, pool, b0);
  }
  k_bind<<<B_TOT, 64, 0, stream>>>(pool, bind_w, bind_b, outp);
}